// Round 24
// baseline (49.338 us; speedup 1.0000x reference)
//
#include <hip/hip_runtime.h>
#include <hip/hip_fp16.h>
#include <hip/hip_fp8.h>
#include <stdint.h>

typedef __fp16 fp16x2 __attribute__((ext_vector_type(2)));
typedef float f32x4 __attribute__((ext_vector_type(4)));
typedef long lx2 __attribute__((ext_vector_type(2)));

#define NS 4096
#define NTOT 8192
#define DD 256
#define NBLK 2080   // 128x128 tiles: 528 SS tri + 528 TT tri + 1024 ST
#define NPREP 512   // prep blocks (16 rows each; 2 per CU)

// X8 "tiled8p" PAIRED layout (fp8): row-group r>>4 = contiguous 4096B panel;
// with k = 64g + 32p + 8h + j:  byte(r,k) = g*1024 + h*256 + (r&15)*16 + p*8 + j.
// ONE 16B/lane dwordx4 (1KB/wave contiguous) feeds a lane's fragments for
// BOTH kt=2g and kt=2g+1. (r21/r23-verified: absmax 7.6e-6, best 46.1.)

// workspace layout (bytes)
#define OFF_X8    0                        // 2 MB fp8 (tiled8p)
#define OFF_SQQ   (2*1024*1024)            // 8192 floats (quantized row sq)
#define OFF_SQP   (OFF_SQQ + 32*1024)      // 8192 floats (-cl2*sqq)
#define OFF_SQ    (OFF_SQP + 32*1024)      // 8192 floats (exact, for bw)
#define OFF_COLP  (OFF_SQ + 32*1024)       // 512*256 floats (exact col partials)
#define OFF_BP    (OFF_COLP + 512*1024)    // 2080 floats
#define OFF_SCAL  (OFF_BP + 8320)          // 1 float (cl2)

// ---------------------------------------------------------------- K1: prep
// (r23-proven) 512 blocks x 256 threads; block b = rows [16b,16b+16) = one
// tiled8p panel. fp8-e4m3 quantize; sq exact (bw), sqq from dequantized.
__global__ __launch_bounds__(256) void mmd_prep(const float* __restrict__ S,
                                                const float* __restrict__ T,
                                                uint8_t* __restrict__ X8,
                                                float* __restrict__ sq,
                                                float* __restrict__ sqq,
                                                float* __restrict__ colpart) {
    __shared__ uint8_t tile[16][264];      // +8B pad
    __shared__ float cl[4][256];
    const int b = blockIdx.x, tid = threadIdx.x;
    const int lane = tid & 63, w = tid >> 6;
    f32x4 cacc = {0.f, 0.f, 0.f, 0.f};
    #pragma unroll
    for (int rr = 0; rr < 4; ++rr) {
        const int row = b * 16 + w * 4 + rr;               // wave-uniform
        const float* src = (row < NS) ? (S + (size_t)row * DD)
                                      : (T + (size_t)(row - NS) * DD);
        const f32x4 v = *(const f32x4*)(src + lane * 4);
        cacc += v;
        float vv_e = v.x * v.x + v.y * v.y + v.z * v.z + v.w * v.w;
        const __hip_fp8_storage_t q0 = __hip_cvt_float_to_fp8(v.x, __HIP_SATFINITE, __HIP_E4M3);
        const __hip_fp8_storage_t q1 = __hip_cvt_float_to_fp8(v.y, __HIP_SATFINITE, __HIP_E4M3);
        const __hip_fp8_storage_t q2 = __hip_cvt_float_to_fp8(v.z, __HIP_SATFINITE, __HIP_E4M3);
        const __hip_fp8_storage_t q3 = __hip_cvt_float_to_fp8(v.w, __HIP_SATFINITE, __HIP_E4M3);
        const float f0 = __half2float(__half(__hip_cvt_fp8_to_halfraw(q0, __HIP_E4M3)));
        const float f1 = __half2float(__half(__hip_cvt_fp8_to_halfraw(q1, __HIP_E4M3)));
        const float f2 = __half2float(__half(__hip_cvt_fp8_to_halfraw(q2, __HIP_E4M3)));
        const float f3 = __half2float(__half(__hip_cvt_fp8_to_halfraw(q3, __HIP_E4M3)));
        float vv_q = f0 * f0 + f1 * f1 + f2 * f2 + f3 * f3;
        const uint32_t packed = (uint32_t)q0 | ((uint32_t)q1 << 8) |
                                ((uint32_t)q2 << 16) | ((uint32_t)q3 << 24);
        *(uint32_t*)&tile[w * 4 + rr][lane * 4] = packed;
        #pragma unroll
        for (int off = 32; off; off >>= 1) {
            vv_e += __shfl_down(vv_e, off);
            vv_q += __shfl_down(vv_q, off);
        }
        if (lane == 0) { sq[row] = vv_e; sqq[row] = vv_q; }
    }
    __syncthreads();
    {
        uint8_t* dst = X8 + (size_t)b * 4096;
        const int g = tid >> 6, hh = (tid >> 4) & 3, rl = tid & 15;
        const uint2 lo  = *(const uint2*)&tile[rl][g * 64 + hh * 8];
        const uint2 hi2 = *(const uint2*)&tile[rl][g * 64 + 32 + hh * 8];
        const uint4 val = {lo.x, lo.y, hi2.x, hi2.y};
        *(uint4*)(dst + tid * 16) = val;
    }
    *(f32x4*)&cl[w][lane * 4] = cacc;
    __syncthreads();
    colpart[b * 256 + tid] = cl[0][tid] + cl[1][tid] + cl[2][tid] + cl[3][tid];
}

// ---------------------------------------------------------------- K2: bandwidth (+sqp fill)
__global__ __launch_bounds__(1024) void mmd_bw(const float* __restrict__ colpart,
                                               const float* __restrict__ sq,
                                               const float* __restrict__ sqq,
                                               float* __restrict__ scal,
                                               float* __restrict__ sqp) {
    __shared__ float cpart[4][256];
    __shared__ double sd[16], sf[16];
    __shared__ float cl2sh;
    const int t = threadIdx.x;
    const int c = t & 255, g = t >> 8;
    float cs = 0.0f;
    #pragma unroll 8
    for (int b = 0; b < 128; ++b) cs += colpart[((g * 128 + b) << 8) | c];
    cpart[g][c] = cs;
    const f32x4 q0 = *(const f32x4*)(sq + t * 8);
    const f32x4 q1 = *(const f32x4*)(sq + t * 8 + 4);
    double qd = (double)(q0.x + q0.y + q0.z + q0.w) +
                (double)(q1.x + q1.y + q1.z + q1.w);
    __syncthreads();
    double s2 = 0.0;
    if (g == 0) {
        const double tot = (double)cpart[0][c] + cpart[1][c] +
                           cpart[2][c] + cpart[3][c];
        s2 = tot * tot;
    }
    const int lane = t & 63, w = t >> 6;
    #pragma unroll
    for (int off = 32; off; off >>= 1) {
        s2 += __shfl_down(s2, off);
        qd += __shfl_down(qd, off);
    }
    if (lane == 0) { sd[w] = s2; sf[w] = qd; }
    __syncthreads();
    if (t == 0) {
        double s2t = 0.0, qt = 0.0;
        #pragma unroll
        for (int i = 0; i < 16; ++i) { s2t += sd[i]; qt += sf[i]; }
        const double n = (double)NTOT;
        const double sumd2 = 2.0 * n * qt - 2.0 * s2t;
        double bwv = sumd2 / (n * n - n);
        bwv = bwv / 4.0;   // KERNEL_MUL^(KERNEL_NUM//2) = 2^2
        const float cl2 = (float)(1.0 / (16.0 * bwv * 0.6931471805599453));
        scal[0] = cl2;
        cl2sh = cl2;
    }
    __syncthreads();
    const float mcl2 = -cl2sh;
    #pragma unroll
    for (int k = 0; k < 8; ++k)
        sqp[t + k * 1024] = mcl2 * sqq[t + k * 1024];
}

// ---------------------------------------------------------------- K3: main (fp8 paired, 128x64 waves)
// 2080 blocks x 128 threads (2 waves), 128x128 tile; wave w covers ALL 128
// rows x cols [w*64,+64): A-fragments amortize over 2x output vs r23 ->
// -25% L2 requests AND traffic (the only lever that has ever moved main:
// r15 -5us, r21 -4.3us). acc[8][4] ~200 VGPR (cap 256 via bounds(128,2));
// occupancy 2 waves/SIMD proven non-binding (r15==r16).
__global__ __launch_bounds__(128, 2) void mmd_main(const uint8_t* __restrict__ X8,
                                                   const float* __restrict__ sqp,
                                                   const float* __restrict__ scal,
                                                   float* __restrict__ blockpart) {
    __shared__ float wsum[2];

    // T1: XCD swizzle (2080 % 8 == 0 -> bijective simple form)
    const int bid = (blockIdx.x & 7) * (NBLK / 8) + (blockIdx.x >> 3);
    int br, bc;
    float wfac;
    if (bid < 1056) {
        int t = bid, base = 0;
        if (t >= 528) { t -= 528; base = 32; }
        int i = (int)((sqrtf(8.0f * (float)t + 1.0f) - 1.0f) * 0.5f);
        while ((i + 1) * (i + 2) / 2 <= t) ++i;
        while (i * (i + 1) / 2 > t) --i;
        const int j = t - i * (i + 1) / 2;
        br = base + i; bc = base + j;
        wfac = (i == j) ? 1.0f : 2.0f;     // off-diag tile counts for (i,j) and (j,i)
    } else {
        const int t = bid - 1056;
        br = t >> 5; bc = 32 + (t & 31);
        wfac = -2.0f;                      // loss has -2*xy
    }
    const int row0 = br * 128, col0 = bc * 128;
    const int tid = threadIdx.x;
    const int lane = tid & 63;
    const int w = tid >> 6;                // wave = col half (0,1)
    const int rA = lane & 15, hi = lane >> 4;
    const int lofp = hi * 256 + rA * 16;   // paired-layout lane byte offset

    const uint8_t* Abase = X8 + (size_t)(row0 >> 4) * 4096 + lofp;
    const uint8_t* Bbase = X8 + ((size_t)(col0 >> 4) + w * 4) * 4096 + lofp;

    f32x4 acc[8][4] = {};
    #pragma unroll
    for (int g = 0; g < 4; ++g) {          // g = kt pair (kt = 2g, 2g+1)
        lx2 a[8], b[4];
        #pragma unroll
        for (int m = 0; m < 8; ++m)
            a[m] = *(const lx2*)(Abase + (size_t)m * 4096 + g * 1024);
        #pragma unroll
        for (int n = 0; n < 4; ++n)
            b[n] = *(const lx2*)(Bbase + (size_t)n * 4096 + g * 1024);
        __builtin_amdgcn_s_setprio(1);
        #pragma unroll
        for (int m = 0; m < 8; ++m)
            #pragma unroll
            for (int n = 0; n < 4; ++n)
                acc[m][n] = __builtin_amdgcn_mfma_f32_16x16x32_fp8_fp8(
                    a[m][0], b[n][0], acc[m][n], 0, 0, 0);
        #pragma unroll
        for (int m = 0; m < 8; ++m)
            #pragma unroll
            for (int n = 0; n < 4; ++n)
                acc[m][n] = __builtin_amdgcn_mfma_f32_16x16x32_fp8_fp8(
                    a[m][1], b[n][1], acc[m][n], 0, 0, 0);
        __builtin_amdgcn_s_setprio(0);
    }

    // epilogue: x = g*2cl2 + sip+sj; e = 2^x; sum e+e^2+e^4+e^8+e^16
    const float c2 = 2.0f * scal[0];
    const fp16x2 one2 = {(__fp16)1.0f, (__fp16)1.0f};
    float sj[4];
    #pragma unroll
    for (int nf = 0; nf < 4; ++nf)
        sj[nf] = sqp[col0 + w * 64 + nf * 16 + rA];

    float part = 0.0f;
    #pragma unroll
    for (int m = 0; m < 8; ++m) {
        const f32x4 sipv = *(const f32x4*)&sqp[row0 + m * 16 + hi * 4];
        #pragma unroll
        for (int nf = 0; nf < 4; ++nf)
            #pragma unroll
            for (int rp = 0; rp < 2; ++rp) {
                const float x0 = fmaf(acc[m][nf][2 * rp],     c2,
                                      sipv[2 * rp]     + sj[nf]);
                const float x1 = fmaf(acc[m][nf][2 * rp + 1], c2,
                                      sipv[2 * rp + 1] + sj[nf]);
                const float e0 = exp2f(x0);
                const float e1 = exp2f(x1);
                fp16x2 h  = __builtin_amdgcn_cvt_pkrtz(e0, e1);
                fp16x2 p2 = h * h;           // e^2
                fp16x2 ks = h + p2;
                p2 = p2 * p2; ks += p2;      // e^4
                p2 = p2 * p2; ks += p2;      // e^8
                p2 = p2 * p2; ks += p2;      // e^16
#if __has_builtin(__builtin_amdgcn_fdot2)
                part = __builtin_amdgcn_fdot2(ks, one2, part, false);
#else
                part += (float)ks.x + (float)ks.y;
#endif
            }
    }

    #pragma unroll
    for (int off = 32; off > 0; off >>= 1) part += __shfl_down(part, off);
    if (lane == 0) wsum[w] = part;
    __syncthreads();
    if (tid == 0)
        blockpart[bid] = (wsum[0] + wsum[1]) * wfac;
}

// ---------------------------------------------------------------- K4: final reduce
__global__ __launch_bounds__(512) void mmd_final(const float* __restrict__ blockpart,
                                                 float* __restrict__ out) {
    const int t = threadIdx.x;
    double acc = 0.0;
    #pragma unroll
    for (int u = 0; u < 4; ++u) acc += (double)blockpart[t + u * 512];
    if (t < NBLK - 2048) acc += (double)blockpart[t + 2048];
    #pragma unroll
    for (int off = 32; off > 0; off >>= 1) acc += __shfl_down(acc, off);
    __shared__ double sd[8];
    const int lane = t & 63, w = t >> 6;
    if (lane == 0) sd[w] = acc;
    __syncthreads();
    if (t == 0) {
        double tot = 0.0;
        #pragma unroll
        for (int i = 0; i < 8; ++i) tot += sd[i];
        tot /= ((double)NS * (double)NS);
        out[0] = (float)fmax(tot, 0.0);
    }
}

// ---------------------------------------------------------------- launch
extern "C" void kernel_launch(void* const* d_in, const int* in_sizes, int n_in,
                              void* d_out, int out_size, void* d_ws, size_t ws_size,
                              hipStream_t stream) {
    const float* S = (const float*)d_in[0];
    const float* T = (const float*)d_in[1];
    char* ws = (char*)d_ws;
    uint8_t* X8     = (uint8_t*)(ws + OFF_X8);
    float* sq       = (float*)(ws + OFF_SQ);
    float* sqq      = (float*)(ws + OFF_SQQ);
    float* sqp      = (float*)(ws + OFF_SQP);
    float* colpart  = (float*)(ws + OFF_COLP);
    float* blockpart= (float*)(ws + OFF_BP);
    float* scal     = (float*)(ws + OFF_SCAL);

    mmd_prep<<<NPREP, 256, 0, stream>>>(S, T, X8, sq, sqq, colpart);
    mmd_bw<<<1, 1024, 0, stream>>>(colpart, sq, sqq, scal, sqp);
    mmd_main<<<NBLK, 128, 0, stream>>>(X8, sqp, scal, blockpart);
    mmd_final<<<1, 512, 0, stream>>>(blockpart, (float*)d_out);
}

// Round 25
// 45.864 us; speedup vs baseline: 1.0758x; 1.0758x over previous
//
#include <hip/hip_runtime.h>
#include <hip/hip_fp16.h>
#include <hip/hip_fp8.h>
#include <stdint.h>

typedef __fp16 fp16x2 __attribute__((ext_vector_type(2)));
typedef float f32x4 __attribute__((ext_vector_type(4)));
typedef long lx2 __attribute__((ext_vector_type(2)));

#define NS 4096
#define NTOT 8192
#define DD 256
#define NBLK 2080   // 128x128 tiles: 528 SS tri + 528 TT tri + 1024 ST
#define NPREP 512   // prep blocks (16 rows each; 2 per CU; NO cross-block atomics)

// X8 "tiled8p" PAIRED layout (fp8): row-group r>>4 = contiguous 4096B panel;
// with k = 64g + 32p + 8h + j:  byte(r,k) = g*1024 + h*256 + (r&15)*16 + p*8 + j.
// ONE 16B/lane dwordx4 (1KB/wave contiguous) feeds a lane's fragments for
// BOTH kt=2g and kt=2g+1. (r21/r23-verified: absmax 7.6e-6, best total 46.1.)

// workspace layout (bytes)
#define OFF_X8    0                        // 2 MB fp8 (tiled8p)
#define OFF_SQQ   (2*1024*1024)            // 8192 floats (quantized row sq)
#define OFF_SQP   (OFF_SQQ + 32*1024)      // 8192 floats (-cl2*sqq)
#define OFF_SQ    (OFF_SQP + 32*1024)      // 8192 floats (exact, for bw)
#define OFF_COLP  (OFF_SQ + 32*1024)       // 512*256 floats (exact col partials)
#define OFF_BP    (OFF_COLP + 512*1024)    // 2080 floats
#define OFF_SCAL  (OFF_BP + 8320)          // 1 float (cl2)

// ---------------------------------------------------------------- K1: prep
// 512 blocks x 256 threads (2/CU, 8 waves/CU); block b handles rows
// [16b,16b+16) = ONE tiled8p panel. fp8-e4m3 quantize; sq (exact) for bw,
// sqq (from dequantized values) so main's d2 >= 0 exactly. Plain per-block
// colpart stores — NO atomics/fences (r22 lesson: 53us contention).
__global__ __launch_bounds__(256) void mmd_prep(const float* __restrict__ S,
                                                const float* __restrict__ T,
                                                uint8_t* __restrict__ X8,
                                                float* __restrict__ sq,
                                                float* __restrict__ sqq,
                                                float* __restrict__ colpart) {
    __shared__ uint8_t tile[16][264];      // +8B pad
    __shared__ float cl[4][256];
    const int b = blockIdx.x, tid = threadIdx.x;
    const int lane = tid & 63, w = tid >> 6;
    f32x4 cacc = {0.f, 0.f, 0.f, 0.f};
    #pragma unroll
    for (int rr = 0; rr < 4; ++rr) {
        const int row = b * 16 + w * 4 + rr;               // wave-uniform
        const float* src = (row < NS) ? (S + (size_t)row * DD)
                                      : (T + (size_t)(row - NS) * DD);
        const f32x4 v = *(const f32x4*)(src + lane * 4);
        cacc += v;
        float vv_e = v.x * v.x + v.y * v.y + v.z * v.z + v.w * v.w;
        const __hip_fp8_storage_t q0 = __hip_cvt_float_to_fp8(v.x, __HIP_SATFINITE, __HIP_E4M3);
        const __hip_fp8_storage_t q1 = __hip_cvt_float_to_fp8(v.y, __HIP_SATFINITE, __HIP_E4M3);
        const __hip_fp8_storage_t q2 = __hip_cvt_float_to_fp8(v.z, __HIP_SATFINITE, __HIP_E4M3);
        const __hip_fp8_storage_t q3 = __hip_cvt_float_to_fp8(v.w, __HIP_SATFINITE, __HIP_E4M3);
        const float f0 = __half2float(__half(__hip_cvt_fp8_to_halfraw(q0, __HIP_E4M3)));
        const float f1 = __half2float(__half(__hip_cvt_fp8_to_halfraw(q1, __HIP_E4M3)));
        const float f2 = __half2float(__half(__hip_cvt_fp8_to_halfraw(q2, __HIP_E4M3)));
        const float f3 = __half2float(__half(__hip_cvt_fp8_to_halfraw(q3, __HIP_E4M3)));
        float vv_q = f0 * f0 + f1 * f1 + f2 * f2 + f3 * f3;
        const uint32_t packed = (uint32_t)q0 | ((uint32_t)q1 << 8) |
                                ((uint32_t)q2 << 16) | ((uint32_t)q3 << 24);
        *(uint32_t*)&tile[w * 4 + rr][lane * 4] = packed;
        #pragma unroll
        for (int off = 32; off; off >>= 1) {
            vv_e += __shfl_down(vv_e, off);
            vv_q += __shfl_down(vv_q, off);
        }
        if (lane == 0) { sq[row] = vv_e; sqq[row] = vv_q; }
    }
    __syncthreads();
    // write the block's 4096B tiled8p panel: thread tid writes 16B at tid*16:
    // g=tid>>6, hh=(tid>>4)&3, rl=tid&15; bytes = row rl, k=[64g+8hh..+8)
    // (p=0) then k=[64g+32+8hh..+8) (p=1).
    {
        uint8_t* dst = X8 + (size_t)b * 4096;
        const int g = tid >> 6, hh = (tid >> 4) & 3, rl = tid & 15;
        const uint2 lo  = *(const uint2*)&tile[rl][g * 64 + hh * 8];
        const uint2 hi2 = *(const uint2*)&tile[rl][g * 64 + 32 + hh * 8];
        const uint4 val = {lo.x, lo.y, hi2.x, hi2.y};
        *(uint4*)(dst + tid * 16) = val;
    }
    *(f32x4*)&cl[w][lane * 4] = cacc;
    __syncthreads();
    colpart[b * 256 + tid] = cl[0][tid] + cl[1][tid] + cl[2][tid] + cl[3][tid];
}

// ---------------------------------------------------------------- K2: bandwidth (+sqp fill)
// 1 block, 1024 threads. Sums 512 block-partials per column (pipelined
// independent loads). sum(d2) = 2*n*sum(sq) - 2*||colsum||^2.
__global__ __launch_bounds__(1024) void mmd_bw(const float* __restrict__ colpart,
                                               const float* __restrict__ sq,
                                               const float* __restrict__ sqq,
                                               float* __restrict__ scal,
                                               float* __restrict__ sqp) {
    __shared__ float cpart[4][256];
    __shared__ double sd[16], sf[16];
    __shared__ float cl2sh;
    const int t = threadIdx.x;
    const int c = t & 255, g = t >> 8;
    float cs = 0.0f;
    #pragma unroll 8
    for (int b = 0; b < 128; ++b) cs += colpart[((g * 128 + b) << 8) | c];
    cpart[g][c] = cs;
    const f32x4 q0 = *(const f32x4*)(sq + t * 8);
    const f32x4 q1 = *(const f32x4*)(sq + t * 8 + 4);
    double qd = (double)(q0.x + q0.y + q0.z + q0.w) +
                (double)(q1.x + q1.y + q1.z + q1.w);
    __syncthreads();
    double s2 = 0.0;
    if (g == 0) {
        const double tot = (double)cpart[0][c] + cpart[1][c] +
                           cpart[2][c] + cpart[3][c];
        s2 = tot * tot;
    }
    const int lane = t & 63, w = t >> 6;
    #pragma unroll
    for (int off = 32; off; off >>= 1) {
        s2 += __shfl_down(s2, off);
        qd += __shfl_down(qd, off);
    }
    if (lane == 0) { sd[w] = s2; sf[w] = qd; }
    __syncthreads();
    if (t == 0) {
        double s2t = 0.0, qt = 0.0;
        #pragma unroll
        for (int i = 0; i < 16; ++i) { s2t += sd[i]; qt += sf[i]; }
        const double n = (double)NTOT;
        const double sumd2 = 2.0 * n * qt - 2.0 * s2t;
        double bwv = sumd2 / (n * n - n);
        bwv = bwv / 4.0;   // KERNEL_MUL^(KERNEL_NUM//2) = 2^2
        const float cl2 = (float)(1.0 / (16.0 * bwv * 0.6931471805599453));
        scal[0] = cl2;
        cl2sh = cl2;
    }
    __syncthreads();
    const float mcl2 = -cl2sh;
    #pragma unroll
    for (int k = 0; k < 8; ++k)
        sqp[t + k * 1024] = mcl2 * sqq[t + k * 1024];
}

// ---------------------------------------------------------------- K3: main (fp8 paired, NO-LDS)
// BIT-IDENTICAL to r21/r23's proven main (best total 46.1): 2080 blocks x
// 256 threads, 128x128 tile, wave = 64x64 quadrant, ONE 16B dwordx4/lane
// feeds TWO kt fragments (32 loads + 128 MFMA per wave). No LDS, no barriers.
__global__ __launch_bounds__(256, 4) void mmd_main(const uint8_t* __restrict__ X8,
                                                   const float* __restrict__ sqp,
                                                   const float* __restrict__ scal,
                                                   float* __restrict__ blockpart) {
    __shared__ float wsum[4];

    // T1: XCD swizzle (2080 % 8 == 0 -> bijective simple form)
    const int bid = (blockIdx.x & 7) * (NBLK / 8) + (blockIdx.x >> 3);
    int br, bc;
    float wfac;
    if (bid < 1056) {
        int t = bid, base = 0;
        if (t >= 528) { t -= 528; base = 32; }
        int i = (int)((sqrtf(8.0f * (float)t + 1.0f) - 1.0f) * 0.5f);
        while ((i + 1) * (i + 2) / 2 <= t) ++i;
        while (i * (i + 1) / 2 > t) --i;
        const int j = t - i * (i + 1) / 2;
        br = base + i; bc = base + j;
        wfac = (i == j) ? 1.0f : 2.0f;     // off-diag tile counts for (i,j) and (j,i)
    } else {
        const int t = bid - 1056;
        br = t >> 5; bc = 32 + (t & 31);
        wfac = -2.0f;                      // loss has -2*xy
    }
    const int row0 = br * 128, col0 = bc * 128;
    const int tid = threadIdx.x;
    const int lane = tid & 63;
    const int w = tid >> 6;
    const int rh = w >> 1, ch = w & 1;     // 2x2 wave split: 64x64 each
    const int rA = lane & 15, hi = lane >> 4;
    const int lofp = hi * 256 + rA * 16;   // paired-layout lane byte offset

    const uint8_t* Abase = X8 + ((size_t)(row0 >> 4) + rh * 4) * 4096 + lofp;
    const uint8_t* Bbase = X8 + ((size_t)(col0 >> 4) + ch * 4) * 4096 + lofp;

    f32x4 acc[4][4] = {};
    #pragma unroll
    for (int g = 0; g < 4; ++g) {          // g = kt pair (kt = 2g, 2g+1)
        lx2 a[4], b[4];
        #pragma unroll
        for (int m = 0; m < 4; ++m)
            a[m] = *(const lx2*)(Abase + (size_t)m * 4096 + g * 1024);
        #pragma unroll
        for (int n = 0; n < 4; ++n)
            b[n] = *(const lx2*)(Bbase + (size_t)n * 4096 + g * 1024);
        __builtin_amdgcn_s_setprio(1);
        #pragma unroll
        for (int m = 0; m < 4; ++m)
            #pragma unroll
            for (int n = 0; n < 4; ++n)
                acc[m][n] = __builtin_amdgcn_mfma_f32_16x16x32_fp8_fp8(
                    a[m][0], b[n][0], acc[m][n], 0, 0, 0);
        #pragma unroll
        for (int m = 0; m < 4; ++m)
            #pragma unroll
            for (int n = 0; n < 4; ++n)
                acc[m][n] = __builtin_amdgcn_mfma_f32_16x16x32_fp8_fp8(
                    a[m][1], b[n][1], acc[m][n], 0, 0, 0);
        __builtin_amdgcn_s_setprio(0);
    }

    // epilogue: x = g*2cl2 + sip+sj; e = 2^x; sum e+e^2+e^4+e^8+e^16
    const float c2 = 2.0f * scal[0];
    const fp16x2 one2 = {(__fp16)1.0f, (__fp16)1.0f};
    float sj[4];
    #pragma unroll
    for (int nf = 0; nf < 4; ++nf)
        sj[nf] = sqp[col0 + ch * 64 + nf * 16 + rA];

    float part = 0.0f;
    #pragma unroll
    for (int m = 0; m < 4; ++m) {
        const f32x4 sipv = *(const f32x4*)&sqp[row0 + rh * 64 + m * 16 + hi * 4];
        #pragma unroll
        for (int nf = 0; nf < 4; ++nf)
            #pragma unroll
            for (int rp = 0; rp < 2; ++rp) {
                const float x0 = fmaf(acc[m][nf][2 * rp],     c2,
                                      sipv[2 * rp]     + sj[nf]);
                const float x1 = fmaf(acc[m][nf][2 * rp + 1], c2,
                                      sipv[2 * rp + 1] + sj[nf]);
                const float e0 = exp2f(x0);
                const float e1 = exp2f(x1);
                fp16x2 h  = __builtin_amdgcn_cvt_pkrtz(e0, e1);
                fp16x2 p2 = h * h;           // e^2
                fp16x2 ks = h + p2;
                p2 = p2 * p2; ks += p2;      // e^4
                p2 = p2 * p2; ks += p2;      // e^8
                p2 = p2 * p2; ks += p2;      // e^16
#if __has_builtin(__builtin_amdgcn_fdot2)
                part = __builtin_amdgcn_fdot2(ks, one2, part, false);
#else
                part += (float)ks.x + (float)ks.y;
#endif
            }
    }

    #pragma unroll
    for (int off = 32; off > 0; off >>= 1) part += __shfl_down(part, off);
    if (lane == 0) wsum[w] = part;
    __syncthreads();
    if (tid == 0)
        blockpart[bid] = (wsum[0] + wsum[1] + wsum[2] + wsum[3]) * wfac;
}

// ---------------------------------------------------------------- K4: final reduce
__global__ __launch_bounds__(512) void mmd_final(const float* __restrict__ blockpart,
                                                 float* __restrict__ out) {
    const int t = threadIdx.x;
    double acc = 0.0;
    #pragma unroll
    for (int u = 0; u < 4; ++u) acc += (double)blockpart[t + u * 512];
    if (t < NBLK - 2048) acc += (double)blockpart[t + 2048];
    #pragma unroll
    for (int off = 32; off > 0; off >>= 1) acc += __shfl_down(acc, off);
    __shared__ double sd[8];
    const int lane = t & 63, w = t >> 6;
    if (lane == 0) sd[w] = acc;
    __syncthreads();
    if (t == 0) {
        double tot = 0.0;
        #pragma unroll
        for (int i = 0; i < 8; ++i) tot += sd[i];
        tot /= ((double)NS * (double)NS);
        out[0] = (float)fmax(tot, 0.0);
    }
}

// ---------------------------------------------------------------- launch
extern "C" void kernel_launch(void* const* d_in, const int* in_sizes, int n_in,
                              void* d_out, int out_size, void* d_ws, size_t ws_size,
                              hipStream_t stream) {
    const float* S = (const float*)d_in[0];
    const float* T = (const float*)d_in[1];
    char* ws = (char*)d_ws;
    uint8_t* X8     = (uint8_t*)(ws + OFF_X8);
    float* sq       = (float*)(ws + OFF_SQ);
    float* sqq      = (float*)(ws + OFF_SQQ);
    float* sqp      = (float*)(ws + OFF_SQP);
    float* colpart  = (float*)(ws + OFF_COLP);
    float* blockpart= (float*)(ws + OFF_BP);
    float* scal     = (float*)(ws + OFF_SCAL);

    mmd_prep<<<NPREP, 256, 0, stream>>>(S, T, X8, sq, sqq, colpart);
    mmd_bw<<<1, 1024, 0, stream>>>(colpart, sq, sqq, scal, sqp);
    mmd_main<<<NBLK, 256, 0, stream>>>(X8, sqp, scal, blockpart);
    mmd_final<<<1, 512, 0, stream>>>(blockpart, (float*)d_out);
}